// Round 7
// baseline (211.879 us; speedup 1.0000x reference)
//
#include <hip/hip_runtime.h>
#include <math.h>

#define C 256
#define S 4096
#define NH 8
#define NSG 16        // s-groups per bn (256 s each) = Mp partial groups
#define NSTRIP 64     // 64-s strips per bn = LP/ZP granularity
#define EPS 1e-5f
#define SCALE 0.17677669529663687f   // 1/sqrt(32)

// workspace layout (float offsets)
#define OFF_GW  0                  // 64*256*8 = 131072 ([bn][c][h])
#define OFF_G   131072             // 512
#define OFF_BC  131584             // 512
#define OFF_LP  132096             // 512*64 = 32768
#define OFF_ZP  164864             // 32768
#define OFF_IL  197632             // 512
#define OFF_Z   198144             // 512
#define OFF_MP  198656             // 16*64*256*8 = 2097152
#define OFF_WEI 2295808            // 64*8*256 = 131072

// ---------------------------------------------------------------------------
// K1: LN(mask_tokens) -> q -> fold q into Wk. gw stored TRANSPOSED [c][h].
// ---------------------------------------------------------------------------
__global__ __launch_bounds__(256) void k1_prep(
    const float* __restrict__ mt, const float* __restrict__ ln_t_w, const float* __restrict__ ln_t_b,
    const float* __restrict__ ln_p_w, const float* __restrict__ ln_p_b,
    const float* __restrict__ Wq, const float* __restrict__ bq,
    const float* __restrict__ Wk, const float* __restrict__ bk,
    float* __restrict__ gw, float* __restrict__ Gv, float* __restrict__ Bc)
{
    int bn  = blockIdx.x;
    int tid = threadIdx.x;
    int wid = tid >> 6, lane = tid & 63;
    __shared__ float nt[C];
    __shared__ float qv[C];
    __shared__ float wks[NH][C];
    __shared__ float red[8];

    float x  = mt[bn * C + tid];
    float s1 = x, s2 = x * x;
    #pragma unroll
    for (int off = 32; off; off >>= 1) {
        s1 += __shfl_xor(s1, off);
        s2 += __shfl_xor(s2, off);
    }
    if (lane == 0) { red[wid] = s1; red[4 + wid] = s2; }
    __syncthreads();
    float mu   = (red[0] + red[1] + red[2] + red[3]) * (1.0f / C);
    float msq  = (red[4] + red[5] + red[6] + red[7]) * (1.0f / C);
    float rstd = rsqrtf(msq - mu * mu + EPS);
    nt[tid] = (x - mu) * rstd * ln_t_w[tid] + ln_t_b[tid];
    __syncthreads();

    {   // q[j=tid] = nt . Wq[j,:] + bq[j]
        float acc = bq[tid];
        const float* wrow = Wq + (size_t)tid * C;
        #pragma unroll 8
        for (int c = 0; c < C; ++c) acc += nt[c] * wrow[c];
        qv[tid] = acc;
    }
    __syncthreads();

    int c = tid;
    #pragma unroll
    for (int h = 0; h < NH; ++h) {
        float a = 0.f;
        #pragma unroll 4
        for (int d = 0; d < 32; ++d) a += qv[h * 32 + d] * Wk[(size_t)(h * 32 + d) * C + c];
        wks[h][c] = a * SCALE;
    }
    __syncthreads();

    for (int i = tid; i < C * NH; i += 256) {
        int cc = i >> 3, h = i & 7;
        gw[(size_t)bn * C * NH + i] = ln_p_w[cc] * wks[h][cc];
    }

    {
        int h = tid >> 5, l32 = tid & 31;
        float g = 0.f, bs = 0.f;
        #pragma unroll
        for (int cc = l32; cc < C; cc += 32) {
            float w = wks[h][cc];
            g  += ln_p_w[cc] * w;
            bs += ln_p_b[cc] * w;
        }
        float qb = qv[h * 32 + l32] * bk[h * 32 + l32];
        #pragma unroll
        for (int off = 16; off; off >>= 1) {
            g  += __shfl_xor(g, off);
            bs += __shfl_xor(bs, off);
            qb += __shfl_xor(qb, off);
        }
        if (l32 == 0) {
            Gv[bn * NH + h] = g;
            Bc[bn * NH + h] = bs + qb * SCALE;
        }
    }
}

// ---------------------------------------------------------------------------
// KFUSED v2: block = (bn, 256-s group). NO x-tile in LDS; only pt (8 KB).
// Sweep1 (lane=s): coalesced column stream of x, uniform g loads, stats+
// scores+pt -> LDS; per-wave L/Z partials. ONE barrier. Sweep2 (lane=c):
// row re-read of same region (L2/L3-hot), pt via uniform LDS broadcasts,
// M_unnorm[c][8] in regs -> one coalesced store. Zero other sync.
// ---------------------------------------------------------------------------
__global__ __launch_bounds__(256) void kfused(
    const float* __restrict__ pe, const float* __restrict__ gw,
    const float* __restrict__ Gv, const float* __restrict__ Bc,
    float* __restrict__ LP, float* __restrict__ ZP, float* __restrict__ Mp)
{
    int blk = blockIdx.x;
    int swz = (blk & 7) * 128 + (blk >> 3);   // XCD-contiguous work chunks
    int bn  = swz >> 4;
    int sg  = swz & 15;
    int tid = threadIdx.x;
    int w   = tid >> 6, lane = tid & 63;
    int b = bn >> 3, n = bn & 7;
    const float* xb  = pe + ((size_t)(n * 8 + b)) * C * S;
    const float* gwb = gw + (size_t)bn * C * NH;

    __shared__ float ptb[256][8];   // pt = p*rstd for the block's 256 s

    float Gh[NH], Bh[NH];
    #pragma unroll
    for (int h = 0; h < NH; ++h) { Gh[h] = Gv[bn * NH + h]; Bh[h] = Bc[bn * NH + h]; }

    // ---- sweep 1: lane owns s = sg*256 + tid ----
    {
        const float* xcol = xb + sg * 256 + tid;
        float sum = 0.f, sq = 0.f;
        float A[NH];
        #pragma unroll
        for (int h = 0; h < NH; ++h) A[h] = 0.f;

        #pragma unroll 8
        for (int cc = 0; cc < C; ++cc) {
            float xv = xcol[(size_t)cc * S];
            sum += xv; sq += xv * xv;
            float4 g0 = *reinterpret_cast<const float4*>(gwb + (size_t)cc * NH);
            float4 g1 = *reinterpret_cast<const float4*>(gwb + (size_t)cc * NH + 4);
            A[0] += g0.x * xv; A[1] += g0.y * xv; A[2] += g0.z * xv; A[3] += g0.w * xv;
            A[4] += g1.x * xv; A[5] += g1.y * xv; A[6] += g1.z * xv; A[7] += g1.w * xv;
        }
        float mu   = sum * (1.f / C);
        float var  = sq * (1.f / C) - mu * mu;
        float rs   = rsqrtf(var + EPS);
        float murv = mu * rs;

        float l8[NH], z8[NH];
        float4 pt0, pt1;
        {
            float p0 = __expf(rs * A[0] - murv * Gh[0] + Bh[0]);
            float p1 = __expf(rs * A[1] - murv * Gh[1] + Bh[1]);
            float p2 = __expf(rs * A[2] - murv * Gh[2] + Bh[2]);
            float p3 = __expf(rs * A[3] - murv * Gh[3] + Bh[3]);
            float p4 = __expf(rs * A[4] - murv * Gh[4] + Bh[4]);
            float p5 = __expf(rs * A[5] - murv * Gh[5] + Bh[5]);
            float p6 = __expf(rs * A[6] - murv * Gh[6] + Bh[6]);
            float p7 = __expf(rs * A[7] - murv * Gh[7] + Bh[7]);
            l8[0]=p0; l8[1]=p1; l8[2]=p2; l8[3]=p3; l8[4]=p4; l8[5]=p5; l8[6]=p6; l8[7]=p7;
            #pragma unroll
            for (int h = 0; h < NH; ++h) z8[h] = l8[h] * murv;
            pt0 = make_float4(p0*rs, p1*rs, p2*rs, p3*rs);
            pt1 = make_float4(p4*rs, p5*rs, p6*rs, p7*rs);
        }
        *reinterpret_cast<float4*>(&ptb[tid][0]) = pt0;
        *reinterpret_cast<float4*>(&ptb[tid][4]) = pt1;

        #pragma unroll
        for (int h = 0; h < NH; ++h) {
            float l = l8[h], zz = z8[h];
            #pragma unroll
            for (int off = 32; off; off >>= 1) {
                l  += __shfl_xor(l,  off);
                zz += __shfl_xor(zz, off);
            }
            if (lane == 0) {
                int strip = sg * 4 + w;
                LP[(size_t)(bn * NH + h) * NSTRIP + strip] = l;
                ZP[(size_t)(bn * NH + h) * NSTRIP + strip] = zz;
            }
        }
    }
    __syncthreads();

    // ---- sweep 2: lane owns c = tid; re-read x rows (cache-hot) ----
    {
        int cc = tid;
        const float* row = xb + (size_t)cc * S + sg * 256;
        float acc[NH];
        #pragma unroll
        for (int h = 0; h < NH; ++h) acc[h] = 0.f;

        #pragma unroll
        for (int chunk = 0; chunk < 4; ++chunk) {
            float4 xv[16];
            #pragma unroll
            for (int j = 0; j < 16; ++j)
                xv[j] = reinterpret_cast<const float4*>(row)[chunk * 16 + j];
            const float* xf = reinterpret_cast<const float*>(xv);
            #pragma unroll
            for (int js = 0; js < 64; ++js) {
                int s = chunk * 64 + js;
                float4 p0 = *reinterpret_cast<const float4*>(&ptb[s][0]);
                float4 p1 = *reinterpret_cast<const float4*>(&ptb[s][4]);
                float xx = xf[js];
                acc[0] += p0.x * xx; acc[1] += p0.y * xx; acc[2] += p0.z * xx; acc[3] += p0.w * xx;
                acc[4] += p1.x * xx; acc[5] += p1.y * xx; acc[6] += p1.z * xx; acc[7] += p1.w * xx;
            }
        }
        float* mp = Mp + (((size_t)sg * 64 + bn) * C + cc) * NH;
        *reinterpret_cast<float4*>(mp)     = make_float4(acc[0], acc[1], acc[2], acc[3]);
        *reinterpret_cast<float4*>(mp + 4) = make_float4(acc[4], acc[5], acc[6], acc[7]);
    }
}

// ---------------------------------------------------------------------------
// K3 (tiny): L = sum of 64 strip partials, IL = 1/L, z = Z/L per (bn,h).
// ---------------------------------------------------------------------------
__global__ __launch_bounds__(64) void k3_combine(
    const float* __restrict__ LP, const float* __restrict__ ZP,
    float* __restrict__ IL, float* __restrict__ z)
{
    int idx = blockIdx.x * 64 + threadIdx.x;   // bn*8+h, 512 total
    const float4* lp4 = reinterpret_cast<const float4*>(LP + (size_t)idx * NSTRIP);
    const float4* zp4 = reinterpret_cast<const float4*>(ZP + (size_t)idx * NSTRIP);
    float L = 0.f, Zs = 0.f;
    #pragma unroll
    for (int j = 0; j < 16; ++j) {
        float4 a = lp4[j];
        float4 cz = zp4[j];
        L  += a.x + a.y + a.z + a.w;
        Zs += cz.x + cz.y + cz.z + cz.w;
    }
    float inv = 1.f / L;
    IL[idx] = inv;
    z[idx]  = Zs * inv;
}

// ---------------------------------------------------------------------------
// KFOLD: fold 16 Mp partials, apply IL/z/ln_p -> wei[bn][h][c] global.
// ---------------------------------------------------------------------------
__global__ __launch_bounds__(256) void kfold(
    const float* __restrict__ Mp, const float* __restrict__ IL, const float* __restrict__ z,
    const float* __restrict__ lpw, const float* __restrict__ lpb, float* __restrict__ weig)
{
    int blk = blockIdx.x;
    int bn = blk >> 3, slice = blk & 7;
    int tid = threadIdx.x;
    int c = slice * 32 + (tid >> 3), h = tid & 7;
    float m = 0.f;
    #pragma unroll
    for (int sgi = 0; sgi < NSG; ++sgi)
        m += Mp[(((size_t)sgi * 64 + bn) * C + c) * NH + h];
    float Mn = m * IL[bn * NH + h];
    weig[(size_t)bn * NH * C + h * C + c] = lpw[c] * (Mn - z[bn * NH + h]) + lpb[c];
}

// ---------------------------------------------------------------------------
// K5: wei (global) -> ctx -> Wo -> residual -> MLP -> out. Per-thread serial-K
// GEMVs (L2-hot weight rows, ILP loads).
// ---------------------------------------------------------------------------
__global__ __launch_bounds__(256) void k5_out(
    const float* __restrict__ mt, const float* __restrict__ weig,
    const float* __restrict__ Wv, const float* __restrict__ bv,
    const float* __restrict__ Wo, const float* __restrict__ bo,
    const float* __restrict__ W1, const float* __restrict__ b1,
    const float* __restrict__ W2, const float* __restrict__ b2,
    float* __restrict__ out)
{
    int bn  = blockIdx.x;
    int tid = threadIdx.x;
    __shared__ float wei[NH * C];   // [h][c]
    __shared__ float ctxs[C];
    __shared__ float upds[C];
    __shared__ float hid[2 * C];

    for (int v = tid; v < 512; v += 256)
        *reinterpret_cast<float4*>(&wei[v * 4]) =
            *reinterpret_cast<const float4*>(weig + (size_t)bn * NH * C + v * 4);
    __syncthreads();

    {   // ctx[j=tid] = wei[h(j),:] . Wv[j,:] + bv[j]
        int h = tid >> 5;
        float a = bv[tid];
        const float* wrow = Wv + (size_t)tid * C;
        const float* wh   = wei + h * C;
        #pragma unroll 8
        for (int c2 = 0; c2 < C; ++c2) a += wh[c2] * wrow[c2];
        ctxs[tid] = a;
    }
    __syncthreads();

    float att = bo[tid];
    {
        const float* wrow = Wo + (size_t)tid * C;
        #pragma unroll 8
        for (int j = 0; j < C; ++j) att += ctxs[j] * wrow[j];
    }
    float upd = mt[(size_t)bn * C + tid] + att;
    upds[tid] = upd;
    __syncthreads();

    #pragma unroll
    for (int r = 0; r < 2; ++r) {
        int k = tid + r * 256;
        float a = b1[k];
        const float* wrow = W1 + (size_t)k * C;
        #pragma unroll 8
        for (int c2 = 0; c2 < C; ++c2) a += upds[c2] * wrow[c2];
        hid[k] = fmaxf(a, 0.f);
    }
    __syncthreads();

    float a = b2[tid];
    const float* wrow = W2 + (size_t)tid * 2 * C;
    #pragma unroll 8
    for (int k = 0; k < 2 * C; ++k) a += hid[k] * wrow[k];
    out[(size_t)bn * C + tid] = upd + a;
}

extern "C" void kernel_launch(void* const* d_in, const int* in_sizes, int n_in,
                              void* d_out, int out_size, void* d_ws, size_t ws_size,
                              hipStream_t stream)
{
    const float* mt  = (const float*)d_in[0];
    const float* pe  = (const float*)d_in[1];
    const float* ltw = (const float*)d_in[2];
    const float* ltb = (const float*)d_in[3];
    const float* lpw = (const float*)d_in[4];
    const float* lpb = (const float*)d_in[5];
    const float* Wq  = (const float*)d_in[6];
    const float* bq  = (const float*)d_in[7];
    const float* Wk  = (const float*)d_in[8];
    const float* bk  = (const float*)d_in[9];
    const float* Wv  = (const float*)d_in[10];
    const float* bv  = (const float*)d_in[11];
    const float* Wo  = (const float*)d_in[12];
    const float* bo  = (const float*)d_in[13];
    const float* W1  = (const float*)d_in[14];
    const float* b1  = (const float*)d_in[15];
    const float* W2  = (const float*)d_in[16];
    const float* b2  = (const float*)d_in[17];

    float* ws   = (float*)d_ws;
    float* outp = (float*)d_out;

    float* gw   = ws + OFF_GW;
    float* Gv   = ws + OFF_G;
    float* Bc   = ws + OFF_BC;
    float* LP   = ws + OFF_LP;
    float* ZP   = ws + OFF_ZP;
    float* ILv  = ws + OFF_IL;
    float* z    = ws + OFF_Z;
    float* Mp   = ws + OFF_MP;
    float* weig = ws + OFF_WEI;

    k1_prep   <<<64,   256, 0, stream>>>(mt, ltw, ltb, lpw, lpb, Wq, bq, Wk, bk, gw, Gv, Bc);
    kfused    <<<1024, 256, 0, stream>>>(pe, gw, Gv, Bc, LP, ZP, Mp);
    k3_combine<<<8,    64,  0, stream>>>(LP, ZP, ILv, z);
    kfold     <<<512,  256, 0, stream>>>(Mp, ILv, z, lpw, lpb, weig);
    k5_out    <<<64,   256, 0, stream>>>(mt, weig, Wv, bv, Wo, bo, W1, b1, W2, b2, outp);
}

// Round 8
// 203.411 us; speedup vs baseline: 1.0416x; 1.0416x over previous
//
#include <hip/hip_runtime.h>
#include <math.h>

#define C 256
#define S 4096
#define NH 8
#define NSG 16        // s-groups per bn (256 s each) = Mp partial groups
#define NSTRIP 64     // 64-s strips per bn = LP/ZP granularity
#define EPS 1e-5f
#define SCALE 0.17677669529663687f   // 1/sqrt(32)

// workspace layout (float offsets)
#define OFF_GW  0                  // 64*256*8 = 131072 ([bn][c][h])
#define OFF_G   131072             // 512
#define OFF_BC  131584             // 512
#define OFF_LP  132096             // 512*64 = 32768
#define OFF_ZP  164864             // 32768
#define OFF_IL  197632             // 512
#define OFF_Z   198144             // 512
#define OFF_MP  198656             // 16*64*256*8 = 2097152
#define OFF_WEI 2295808            // 64*8*256 = 131072

__device__ __forceinline__ float bf_lo(unsigned int u) {
    return __builtin_bit_cast(float, u << 16);
}
__device__ __forceinline__ float bf_hi(unsigned int u) {
    return __builtin_bit_cast(float, u & 0xffff0000u);
}
__device__ __forceinline__ unsigned int bf_pack(float a, float b) {
    unsigned int ua = (__builtin_bit_cast(unsigned int, a) + 0x8000u) >> 16;
    unsigned int ub = (__builtin_bit_cast(unsigned int, b) + 0x8000u) & 0xffff0000u;
    return ua | ub;
}

// ---------------------------------------------------------------------------
// K1: LN(mask_tokens) -> q -> fold q into Wk. gw stored TRANSPOSED [c][h].
// ---------------------------------------------------------------------------
__global__ __launch_bounds__(256) void k1_prep(
    const float* __restrict__ mt, const float* __restrict__ ln_t_w, const float* __restrict__ ln_t_b,
    const float* __restrict__ ln_p_w, const float* __restrict__ ln_p_b,
    const float* __restrict__ Wq, const float* __restrict__ bq,
    const float* __restrict__ Wk, const float* __restrict__ bk,
    float* __restrict__ gw, float* __restrict__ Gv, float* __restrict__ Bc)
{
    int bn  = blockIdx.x;
    int tid = threadIdx.x;
    int wid = tid >> 6, lane = tid & 63;
    __shared__ float nt[C];
    __shared__ float qv[C];
    __shared__ float wks[NH][C];
    __shared__ float red[8];

    float x  = mt[bn * C + tid];
    float s1 = x, s2 = x * x;
    #pragma unroll
    for (int off = 32; off; off >>= 1) {
        s1 += __shfl_xor(s1, off);
        s2 += __shfl_xor(s2, off);
    }
    if (lane == 0) { red[wid] = s1; red[4 + wid] = s2; }
    __syncthreads();
    float mu   = (red[0] + red[1] + red[2] + red[3]) * (1.0f / C);
    float msq  = (red[4] + red[5] + red[6] + red[7]) * (1.0f / C);
    float rstd = rsqrtf(msq - mu * mu + EPS);
    nt[tid] = (x - mu) * rstd * ln_t_w[tid] + ln_t_b[tid];
    __syncthreads();

    {   // q[j=tid] = nt . Wq[j,:] + bq[j]
        float acc = bq[tid];
        const float* wrow = Wq + (size_t)tid * C;
        #pragma unroll 8
        for (int c = 0; c < C; ++c) acc += nt[c] * wrow[c];
        qv[tid] = acc;
    }
    __syncthreads();

    int c = tid;
    #pragma unroll
    for (int h = 0; h < NH; ++h) {
        float a = 0.f;
        #pragma unroll 4
        for (int d = 0; d < 32; ++d) a += qv[h * 32 + d] * Wk[(size_t)(h * 32 + d) * C + c];
        wks[h][c] = a * SCALE;
    }
    __syncthreads();

    for (int i = tid; i < C * NH; i += 256) {
        int cc = i >> 3, h = i & 7;
        gw[(size_t)bn * C * NH + i] = ln_p_w[cc] * wks[h][cc];
    }

    {
        int h = tid >> 5, l32 = tid & 31;
        float g = 0.f, bs = 0.f;
        #pragma unroll
        for (int cc = l32; cc < C; cc += 32) {
            float w = wks[h][cc];
            g  += ln_p_w[cc] * w;
            bs += ln_p_b[cc] * w;
        }
        float qb = qv[h * 32 + l32] * bk[h * 32 + l32];
        #pragma unroll
        for (int off = 16; off; off >>= 1) {
            g  += __shfl_xor(g, off);
            bs += __shfl_xor(bs, off);
            qb += __shfl_xor(qb, off);
        }
        if (l32 == 0) {
            Gv[bn * NH + h] = g;
            Bc[bn * NH + h] = bs + qb * SCALE;
        }
    }
}

// ---------------------------------------------------------------------------
// KFUSED v3: block = (bn, 256-s group). pt packed bf16x8 in LDS (4 KB).
// Sweep1 (lane=s): coalesced column stream, uniform scalar g loads, unroll 16.
// Sweep2 (lane=c): row re-read (L3-hot), FULLY UNROLLED inner loop so the
// float4 staging array stays in registers (rule #20), pt via ONE b128
// broadcast per s + 8 unpack VALU.
// ---------------------------------------------------------------------------
__global__ __launch_bounds__(256) void kfused(
    const float* __restrict__ pe, const float* __restrict__ gw,
    const float* __restrict__ Gv, const float* __restrict__ Bc,
    float* __restrict__ LP, float* __restrict__ ZP, float* __restrict__ Mp)
{
    int blk = blockIdx.x;
    int swz = (blk & 7) * 128 + (blk >> 3);   // XCD-contiguous work chunks
    int bn  = swz >> 4;
    int sg  = swz & 15;
    int tid = threadIdx.x;
    int w   = tid >> 6, lane = tid & 63;
    int b = bn >> 3, n = bn & 7;
    const float* xb  = pe + ((size_t)(n * 8 + b)) * C * S;
    const float* gwb = gw + (size_t)bn * C * NH;

    __shared__ unsigned int ptb[256 * 4];   // 4 KB: pt[s][0..7] as bf16 pairs

    float Gh[NH], Bh[NH];
    #pragma unroll
    for (int h = 0; h < NH; ++h) { Gh[h] = Gv[bn * NH + h]; Bh[h] = Bc[bn * NH + h]; }

    // ---- sweep 1: lane owns s = sg*256 + tid ----
    {
        const float* xcol = xb + sg * 256 + tid;
        float sum = 0.f, sq = 0.f;
        float A[NH];
        #pragma unroll
        for (int h = 0; h < NH; ++h) A[h] = 0.f;

        #pragma unroll 16
        for (int cc = 0; cc < C; ++cc) {
            float xv = xcol[(size_t)cc * S];
            sum += xv; sq += xv * xv;
            float4 g0 = *reinterpret_cast<const float4*>(gwb + (size_t)cc * NH);
            float4 g1 = *reinterpret_cast<const float4*>(gwb + (size_t)cc * NH + 4);
            A[0] += g0.x * xv; A[1] += g0.y * xv; A[2] += g0.z * xv; A[3] += g0.w * xv;
            A[4] += g1.x * xv; A[5] += g1.y * xv; A[6] += g1.z * xv; A[7] += g1.w * xv;
        }
        float mu   = sum * (1.f / C);
        float var  = sq * (1.f / C) - mu * mu;
        float rs   = rsqrtf(var + EPS);
        float murv = mu * rs;

        float p[NH];
        #pragma unroll
        for (int h = 0; h < NH; ++h)
            p[h] = __expf(rs * A[h] - murv * Gh[h] + Bh[h]);   // m=0 softmax (validated)

        // pack pt = p*rs as bf16 pairs -> one b128 LDS store
        uint4 pk;
        pk.x = bf_pack(p[0] * rs, p[1] * rs);
        pk.y = bf_pack(p[2] * rs, p[3] * rs);
        pk.z = bf_pack(p[4] * rs, p[5] * rs);
        pk.w = bf_pack(p[6] * rs, p[7] * rs);
        *reinterpret_cast<uint4*>(&ptb[tid * 4]) = pk;

        #pragma unroll
        for (int h = 0; h < NH; ++h) {
            float l = p[h], zz = p[h] * murv;
            #pragma unroll
            for (int off = 32; off; off >>= 1) {
                l  += __shfl_xor(l,  off);
                zz += __shfl_xor(zz, off);
            }
            if (lane == 0) {
                int strip = sg * 4 + w;
                LP[(size_t)(bn * NH + h) * NSTRIP + strip] = l;
                ZP[(size_t)(bn * NH + h) * NSTRIP + strip] = zz;
            }
        }
    }
    __syncthreads();

    // ---- sweep 2: lane owns c = tid; re-read x rows (L3-hot) ----
    {
        int cc = tid;
        const float4* row4 = reinterpret_cast<const float4*>(xb + (size_t)cc * S + sg * 256);
        float acc[NH];
        #pragma unroll
        for (int h = 0; h < NH; ++h) acc[h] = 0.f;

        for (int chunk = 0; chunk < 4; ++chunk) {
            float4 xv[16];
            #pragma unroll
            for (int j = 0; j < 16; ++j) xv[j] = row4[chunk * 16 + j];
            #pragma unroll
            for (int j = 0; j < 16; ++j) {
                float xe0 = xv[j].x, xe1 = xv[j].y, xe2 = xv[j].z, xe3 = xv[j].w;
                #pragma unroll
                for (int e = 0; e < 4; ++e) {
                    int s = chunk * 64 + j * 4 + e;
                    float xx = (e == 0) ? xe0 : (e == 1) ? xe1 : (e == 2) ? xe2 : xe3;
                    uint4 pw = *reinterpret_cast<const uint4*>(&ptb[s * 4]);
                    acc[0] += bf_lo(pw.x) * xx; acc[1] += bf_hi(pw.x) * xx;
                    acc[2] += bf_lo(pw.y) * xx; acc[3] += bf_hi(pw.y) * xx;
                    acc[4] += bf_lo(pw.z) * xx; acc[5] += bf_hi(pw.z) * xx;
                    acc[6] += bf_lo(pw.w) * xx; acc[7] += bf_hi(pw.w) * xx;
                }
            }
        }
        float* mp = Mp + (((size_t)sg * 64 + bn) * C + cc) * NH;
        *reinterpret_cast<float4*>(mp)     = make_float4(acc[0], acc[1], acc[2], acc[3]);
        *reinterpret_cast<float4*>(mp + 4) = make_float4(acc[4], acc[5], acc[6], acc[7]);
    }
}

// ---------------------------------------------------------------------------
// K3 (tiny): L = sum of 64 strip partials, IL = 1/L, z = Z/L per (bn,h).
// ---------------------------------------------------------------------------
__global__ __launch_bounds__(64) void k3_combine(
    const float* __restrict__ LP, const float* __restrict__ ZP,
    float* __restrict__ IL, float* __restrict__ z)
{
    int idx = blockIdx.x * 64 + threadIdx.x;   // bn*8+h, 512 total
    const float4* lp4 = reinterpret_cast<const float4*>(LP + (size_t)idx * NSTRIP);
    const float4* zp4 = reinterpret_cast<const float4*>(ZP + (size_t)idx * NSTRIP);
    float L = 0.f, Zs = 0.f;
    #pragma unroll
    for (int j = 0; j < 16; ++j) {
        float4 a = lp4[j];
        float4 cz = zp4[j];
        L  += a.x + a.y + a.z + a.w;
        Zs += cz.x + cz.y + cz.z + cz.w;
    }
    float inv = 1.f / L;
    IL[idx] = inv;
    z[idx]  = Zs * inv;
}

// ---------------------------------------------------------------------------
// KFOLD: fold 16 Mp partials, apply IL/z/ln_p -> wei[bn][h][c] global.
// ---------------------------------------------------------------------------
__global__ __launch_bounds__(256) void kfold(
    const float* __restrict__ Mp, const float* __restrict__ IL, const float* __restrict__ z,
    const float* __restrict__ lpw, const float* __restrict__ lpb, float* __restrict__ weig)
{
    int blk = blockIdx.x;
    int bn = blk >> 3, slice = blk & 7;
    int tid = threadIdx.x;
    int c = slice * 32 + (tid >> 3), h = tid & 7;
    float m = 0.f;
    #pragma unroll
    for (int sgi = 0; sgi < NSG; ++sgi)
        m += Mp[(((size_t)sgi * 64 + bn) * C + c) * NH + h];
    float Mn = m * IL[bn * NH + h];
    weig[(size_t)bn * NH * C + h * C + c] = lpw[c] * (Mn - z[bn * NH + h]) + lpb[c];
}

// ---------------------------------------------------------------------------
// K5: wei (global) -> ctx -> Wo -> residual -> MLP -> out. Per-thread serial-K
// GEMVs (L2-hot weight rows, ILP loads).
// ---------------------------------------------------------------------------
__global__ __launch_bounds__(256) void k5_out(
    const float* __restrict__ mt, const float* __restrict__ weig,
    const float* __restrict__ Wv, const float* __restrict__ bv,
    const float* __restrict__ Wo, const float* __restrict__ bo,
    const float* __restrict__ W1, const float* __restrict__ b1,
    const float* __restrict__ W2, const float* __restrict__ b2,
    float* __restrict__ out)
{
    int bn  = blockIdx.x;
    int tid = threadIdx.x;
    __shared__ float wei[NH * C];   // [h][c]
    __shared__ float ctxs[C];
    __shared__ float upds[C];
    __shared__ float hid[2 * C];

    for (int v = tid; v < 512; v += 256)
        *reinterpret_cast<float4*>(&wei[v * 4]) =
            *reinterpret_cast<const float4*>(weig + (size_t)bn * NH * C + v * 4);
    __syncthreads();

    {   // ctx[j=tid] = wei[h(j),:] . Wv[j,:] + bv[j]
        int h = tid >> 5;
        float a = bv[tid];
        const float* wrow = Wv + (size_t)tid * C;
        const float* wh   = wei + h * C;
        #pragma unroll 8
        for (int c2 = 0; c2 < C; ++c2) a += wh[c2] * wrow[c2];
        ctxs[tid] = a;
    }
    __syncthreads();

    float att = bo[tid];
    {
        const float* wrow = Wo + (size_t)tid * C;
        #pragma unroll 8
        for (int j = 0; j < C; ++j) att += ctxs[j] * wrow[j];
    }
    float upd = mt[(size_t)bn * C + tid] + att;
    upds[tid] = upd;
    __syncthreads();

    #pragma unroll
    for (int r = 0; r < 2; ++r) {
        int k = tid + r * 256;
        float a = b1[k];
        const float* wrow = W1 + (size_t)k * C;
        #pragma unroll 8
        for (int c2 = 0; c2 < C; ++c2) a += upds[c2] * wrow[c2];
        hid[k] = fmaxf(a, 0.f);
    }
    __syncthreads();

    float a = b2[tid];
    const float* wrow = W2 + (size_t)tid * 2 * C;
    #pragma unroll 8
    for (int k = 0; k < 2 * C; ++k) a += hid[k] * wrow[k];
    out[(size_t)bn * C + tid] = upd + a;
}

extern "C" void kernel_launch(void* const* d_in, const int* in_sizes, int n_in,
                              void* d_out, int out_size, void* d_ws, size_t ws_size,
                              hipStream_t stream)
{
    const float* mt  = (const float*)d_in[0];
    const float* pe  = (const float*)d_in[1];
    const float* ltw = (const float*)d_in[2];
    const float* ltb = (const float*)d_in[3];
    const float* lpw = (const float*)d_in[4];
    const float* lpb = (const float*)d_in[5];
    const float* Wq  = (const float*)d_in[6];
    const float* bq  = (const float*)d_in[7];
    const float* Wk  = (const float*)d_in[8];
    const float* bk  = (const float*)d_in[9];
    const float* Wv  = (const float*)d_in[10];
    const float* bv  = (const float*)d_in[11];
    const float* Wo  = (const float*)d_in[12];
    const float* bo  = (const float*)d_in[13];
    const float* W1  = (const float*)d_in[14];
    const float* b1  = (const float*)d_in[15];
    const float* W2  = (const float*)d_in[16];
    const float* b2  = (const float*)d_in[17];

    float* ws   = (float*)d_ws;
    float* outp = (float*)d_out;

    float* gw   = ws + OFF_GW;
    float* Gv   = ws + OFF_G;
    float* Bc   = ws + OFF_BC;
    float* LP   = ws + OFF_LP;
    float* ZP   = ws + OFF_ZP;
    float* ILv  = ws + OFF_IL;
    float* z    = ws + OFF_Z;
    float* Mp   = ws + OFF_MP;
    float* weig = ws + OFF_WEI;

    k1_prep   <<<64,   256, 0, stream>>>(mt, ltw, ltb, lpw, lpb, Wq, bq, Wk, bk, gw, Gv, Bc);
    kfused    <<<1024, 256, 0, stream>>>(pe, gw, Gv, Bc, LP, ZP, Mp);
    k3_combine<<<8,    64,  0, stream>>>(LP, ZP, ILv, z);
    kfold     <<<512,  256, 0, stream>>>(Mp, ILv, z, lpw, lpb, weig);
    k5_out    <<<64,   256, 0, stream>>>(mt, weig, Wv, bv, Wo, bo, W1, b1, W2, b2, outp);
}

// Round 9
// 193.968 us; speedup vs baseline: 1.0923x; 1.0487x over previous
//
#include <hip/hip_runtime.h>
#include <math.h>

#define C 256
#define S 4096
#define NH 8
#define NSG 16        // s-groups per bn (256 s each) = Mp partial groups
#define NSTRIP 64     // 64-s strips per bn = LP/ZP granularity
#define EPS 1e-5f
#define SCALE 0.17677669529663687f   // 1/sqrt(32)

#define PBS 41        // pbuf row stride (words), coprime with 32 -> conflict-free
#define PTS 272       // ptT row stride (ushorts); 544 B rows keep 16B align, ~4-way

// workspace layout (float offsets)
#define OFF_GW  0                  // 64*256*8 = 131072 ([bn][c][h])
#define OFF_G   131072             // 512
#define OFF_BC  131584             // 512
#define OFF_LP  132096             // 512*64 = 32768
#define OFF_ZP  164864             // 32768
#define OFF_IL  197632             // 512
#define OFF_Z   198144             // 512
#define OFF_MP  198656             // 16*64*256*8 = 2097152
#define OFF_WEI 2295808            // 64*8*256 = 131072

typedef __attribute__((ext_vector_type(8))) short short8;
typedef __attribute__((ext_vector_type(4))) float f32x4;

__device__ __forceinline__ unsigned int bf_pack(float a, float b) {
    unsigned int ua = (__builtin_bit_cast(unsigned int, a) + 0x8000u) >> 16;
    unsigned int ub = (__builtin_bit_cast(unsigned int, b) + 0x8000u) & 0xffff0000u;
    return ua | ub;
}

// ---------------------------------------------------------------------------
// K1: LN(mask_tokens) -> q -> fold q into Wk. gw stored TRANSPOSED [c][h].
// ---------------------------------------------------------------------------
__global__ __launch_bounds__(256) void k1_prep(
    const float* __restrict__ mt, const float* __restrict__ ln_t_w, const float* __restrict__ ln_t_b,
    const float* __restrict__ ln_p_w, const float* __restrict__ ln_p_b,
    const float* __restrict__ Wq, const float* __restrict__ bq,
    const float* __restrict__ Wk, const float* __restrict__ bk,
    float* __restrict__ gw, float* __restrict__ Gv, float* __restrict__ Bc)
{
    int bn  = blockIdx.x;
    int tid = threadIdx.x;
    int wid = tid >> 6, lane = tid & 63;
    __shared__ float nt[C];
    __shared__ float qv[C];
    __shared__ float wks[NH][C];
    __shared__ float red[8];

    float x  = mt[bn * C + tid];
    float s1 = x, s2 = x * x;
    #pragma unroll
    for (int off = 32; off; off >>= 1) {
        s1 += __shfl_xor(s1, off);
        s2 += __shfl_xor(s2, off);
    }
    if (lane == 0) { red[wid] = s1; red[4 + wid] = s2; }
    __syncthreads();
    float mu   = (red[0] + red[1] + red[2] + red[3]) * (1.0f / C);
    float msq  = (red[4] + red[5] + red[6] + red[7]) * (1.0f / C);
    float rstd = rsqrtf(msq - mu * mu + EPS);
    nt[tid] = (x - mu) * rstd * ln_t_w[tid] + ln_t_b[tid];
    __syncthreads();

    {   // q[j=tid] = nt . Wq[j,:] + bq[j]
        float acc = bq[tid];
        const float* wrow = Wq + (size_t)tid * C;
        #pragma unroll 8
        for (int c = 0; c < C; ++c) acc += nt[c] * wrow[c];
        qv[tid] = acc;
    }
    __syncthreads();

    int c = tid;
    #pragma unroll
    for (int h = 0; h < NH; ++h) {
        float a = 0.f;
        #pragma unroll 4
        for (int d = 0; d < 32; ++d) a += qv[h * 32 + d] * Wk[(size_t)(h * 32 + d) * C + c];
        wks[h][c] = a * SCALE;
    }
    __syncthreads();

    for (int i = tid; i < C * NH; i += 256) {
        int cc = i >> 3, h = i & 7;
        gw[(size_t)bn * C * NH + i] = ln_p_w[cc] * wks[h][cc];
    }

    {
        int h = tid >> 5, l32 = tid & 31;
        float g = 0.f, bs = 0.f;
        #pragma unroll
        for (int cc = l32; cc < C; cc += 32) {
            float w = wks[h][cc];
            g  += ln_p_w[cc] * w;
            bs += ln_p_b[cc] * w;
        }
        float qb = qv[h * 32 + l32] * bk[h * 32 + l32];
        #pragma unroll
        for (int off = 16; off; off >>= 1) {
            g  += __shfl_xor(g, off);
            bs += __shfl_xor(bs, off);
            qb += __shfl_xor(qb, off);
        }
        if (l32 == 0) {
            Gv[bn * NH + h] = g;
            Bc[bn * NH + h] = bs + qb * SCALE;
        }
    }
}

// ---------------------------------------------------------------------------
// KFUSED v4: block = (bn, 256-s group), 4 waves.
// Sweep1: wave owns 64-c quarter x 256 s, lane owns 4 consecutive s (float4
// coalesced). Partial stats -> LDS pbuf (stride 41, conflict-free).
// Combine: thread t = s; stats+scores+p; ptT[h][s] bf16 to LDS (16 rows, 8 zero).
// Sweep2: MFMA 16x16x32 bf16: M[c][h] = sum_s x[c,s]*pt[s,h]. A from global
// (L2-hot, 2 float4/lane), B one b128 LDS read. D -> LDS -> coalesced Mp.
// ---------------------------------------------------------------------------
__global__ __launch_bounds__(256) void kfused(
    const float* __restrict__ pe, const float* __restrict__ gw,
    const float* __restrict__ Gv, const float* __restrict__ Bc,
    float* __restrict__ LP, float* __restrict__ ZP, float* __restrict__ Mp)
{
    int blk = blockIdx.x;
    int swz = (blk & 7) * 128 + (blk >> 3);   // XCD-contiguous work chunks
    int bn  = swz >> 4;
    int sg  = swz & 15;
    int tid = threadIdx.x;
    int w   = tid >> 6, lane = tid & 63;
    int b = bn >> 3, n = bn & 7;
    const float* xb  = pe + ((size_t)(n * 8 + b)) * C * S;
    const float* gwb = gw + (size_t)bn * C * NH;
    int sgbase = sg * 256;

    __shared__ float pbuf[256 * PBS];            // 41984 B
    __shared__ unsigned short ptT[16 * PTS];     // 8704 B
    float* Dstage = pbuf;                        // alias (safe after barrier 2)

    // zero ptT rows 8..15 (unused MFMA B columns)
    for (int i = tid; i < 8 * PTS; i += 256) ptT[8 * PTS + i] = 0;

    // ---- sweep 1: wave w owns c in [w*64, w*64+64); lane owns 4 s ----
    {
        float sum[4] = {0.f, 0.f, 0.f, 0.f};
        float sqv[4] = {0.f, 0.f, 0.f, 0.f};
        float A[4][NH];
        #pragma unroll
        for (int e = 0; e < 4; ++e)
            #pragma unroll
            for (int h = 0; h < NH; ++h) A[e][h] = 0.f;

        const float* xq = xb + sgbase + lane * 4;
        #pragma unroll 8
        for (int j = 0; j < 64; ++j) {
            int cc = w * 64 + j;
            float4 xv = *reinterpret_cast<const float4*>(xq + (size_t)cc * S);
            float4 g0 = *reinterpret_cast<const float4*>(gwb + cc * NH);
            float4 g1 = *reinterpret_cast<const float4*>(gwb + cc * NH + 4);
            float xe[4] = {xv.x, xv.y, xv.z, xv.w};
            float ge[8] = {g0.x, g0.y, g0.z, g0.w, g1.x, g1.y, g1.z, g1.w};
            #pragma unroll
            for (int e = 0; e < 4; ++e) {
                sum[e] += xe[e];
                sqv[e] += xe[e] * xe[e];
                #pragma unroll
                for (int h = 0; h < NH; ++h) A[e][h] += ge[h] * xe[e];
            }
        }
        #pragma unroll
        for (int e = 0; e < 4; ++e) {
            float* pb = &pbuf[(lane * 4 + e) * PBS + w * 10];
            pb[0] = sum[e];
            pb[1] = sqv[e];
            #pragma unroll
            for (int h = 0; h < NH; ++h) pb[2 + h] = A[e][h];
        }
    }
    __syncthreads();

    // ---- combine: thread t owns s = t ----
    {
        int t = tid;
        float sum = 0.f, sq = 0.f;
        float A[NH];
        #pragma unroll
        for (int h = 0; h < NH; ++h) A[h] = 0.f;
        #pragma unroll
        for (int wv = 0; wv < 4; ++wv) {
            const float* pb = &pbuf[t * PBS + wv * 10];
            sum += pb[0];
            sq  += pb[1];
            #pragma unroll
            for (int h = 0; h < NH; ++h) A[h] += pb[2 + h];
        }
        float mu   = sum * (1.f / C);
        float var  = sq * (1.f / C) - mu * mu;
        float rs   = rsqrtf(var + EPS);
        float murv = mu * rs;

        float l8[NH], z8[NH];
        #pragma unroll
        for (int h = 0; h < NH; ++h) {
            float sc = rs * A[h] - murv * Gv[bn * NH + h] + Bc[bn * NH + h];
            float p  = __expf(sc);                   // m=0 softmax (validated r4-r8)
            ptT[h * PTS + t] = (unsigned short)(bf_pack(p * rs, 0.f) & 0xffffu);
            l8[h] = p;
            z8[h] = p * murv;
        }
        #pragma unroll
        for (int h = 0; h < NH; ++h) {
            float l = l8[h], zz = z8[h];
            #pragma unroll
            for (int off = 32; off; off >>= 1) {
                l  += __shfl_xor(l,  off);
                zz += __shfl_xor(zz, off);
            }
            if (lane == 0) {
                int strip = sg * 4 + w;
                LP[(size_t)(bn * NH + h) * NSTRIP + strip] = l;
                ZP[(size_t)(bn * NH + h) * NSTRIP + strip] = zz;
            }
        }
    }
    __syncthreads();

    // ---- sweep 2: MFMA. wave w owns c-tiles [w*4, w*4+4) ----
    {
        int mrow = lane & 15;     // A row within tile; B col (= h)
        int kgrp = lane >> 4;     // k block (8 k each)
        #pragma unroll
        for (int ct = 0; ct < 4; ++ct) {
            int ctile = w * 4 + ct;
            int crow  = ctile * 16 + mrow;
            const float* arow = xb + (size_t)crow * S + sgbase + kgrp * 8;
            f32x4 acc = {0.f, 0.f, 0.f, 0.f};
            #pragma unroll
            for (int kc = 0; kc < 8; ++kc) {
                float4 a0 = *reinterpret_cast<const float4*>(arow + kc * 32);
                float4 a1 = *reinterpret_cast<const float4*>(arow + kc * 32 + 4);
                uint4 ap;
                ap.x = bf_pack(a0.x, a0.y);
                ap.y = bf_pack(a0.z, a0.w);
                ap.z = bf_pack(a1.x, a1.y);
                ap.w = bf_pack(a1.z, a1.w);
                short8 af = __builtin_bit_cast(short8, ap);
                uint4 bp = *reinterpret_cast<const uint4*>(&ptT[mrow * PTS + kc * 32 + kgrp * 8]);
                short8 bfv = __builtin_bit_cast(short8, bp);
                acc = __builtin_amdgcn_mfma_f32_16x16x32_bf16(af, bfv, acc, 0, 0, 0);
            }
            if (mrow < NH) {
                #pragma unroll
                for (int r = 0; r < 4; ++r) {
                    int cl = ctile * 16 + kgrp * 4 + r;
                    Dstage[cl * NH + mrow] = acc[r];
                }
            }
        }
    }
    __syncthreads();

    // coalesced Mp write (2048 floats)
    {
        float* mp = Mp + (((size_t)sg * 64 + bn) * C) * NH;
        #pragma unroll
        for (int i = 0; i < 2; ++i) {
            int idx = tid * 8 + i * 4;
            *reinterpret_cast<float4*>(mp + idx) =
                *reinterpret_cast<const float4*>(&Dstage[idx]);
        }
    }
}

// ---------------------------------------------------------------------------
// K3 (tiny): L = sum of 64 strip partials, IL = 1/L, z = Z/L per (bn,h).
// ---------------------------------------------------------------------------
__global__ __launch_bounds__(64) void k3_combine(
    const float* __restrict__ LP, const float* __restrict__ ZP,
    float* __restrict__ IL, float* __restrict__ z)
{
    int idx = blockIdx.x * 64 + threadIdx.x;   // bn*8+h, 512 total
    const float4* lp4 = reinterpret_cast<const float4*>(LP + (size_t)idx * NSTRIP);
    const float4* zp4 = reinterpret_cast<const float4*>(ZP + (size_t)idx * NSTRIP);
    float L = 0.f, Zs = 0.f;
    #pragma unroll
    for (int j = 0; j < 16; ++j) {
        float4 a  = lp4[j];
        float4 cz = zp4[j];
        L  += a.x + a.y + a.z + a.w;
        Zs += cz.x + cz.y + cz.z + cz.w;
    }
    float inv = 1.f / L;
    IL[idx] = inv;
    z[idx]  = Zs * inv;
}

// ---------------------------------------------------------------------------
// KFOLD: fold 16 Mp partials, apply IL/z/ln_p -> wei[bn][h][c] global.
// ---------------------------------------------------------------------------
__global__ __launch_bounds__(256) void kfold(
    const float* __restrict__ Mp, const float* __restrict__ IL, const float* __restrict__ z,
    const float* __restrict__ lpw, const float* __restrict__ lpb, float* __restrict__ weig)
{
    int blk = blockIdx.x;
    int bn = blk >> 3, slice = blk & 7;
    int tid = threadIdx.x;
    int c = slice * 32 + (tid >> 3), h = tid & 7;
    float m = 0.f;
    #pragma unroll
    for (int sgi = 0; sgi < NSG; ++sgi)
        m += Mp[(((size_t)sgi * 64 + bn) * C + c) * NH + h];
    float Mn = m * IL[bn * NH + h];
    weig[(size_t)bn * NH * C + h * C + c] = lpw[c] * (Mn - z[bn * NH + h]) + lpb[c];
}

// ---------------------------------------------------------------------------
// K5: wei (global) -> ctx -> Wo -> residual -> MLP -> out. Per-thread serial-K
// GEMVs (L2-hot weight rows, ILP loads).
// ---------------------------------------------------------------------------
__global__ __launch_bounds__(256) void k5_out(
    const float* __restrict__ mt, const float* __restrict__ weig,
    const float* __restrict__ Wv, const float* __restrict__ bv,
    const float* __restrict__ Wo, const float* __restrict__ bo,
    const float* __restrict__ W1, const float* __restrict__ b1,
    const float* __restrict__ W2, const float* __restrict__ b2,
    float* __restrict__ out)
{
    int bn  = blockIdx.x;
    int tid = threadIdx.x;
    __shared__ float wei[NH * C];   // [h][c]
    __shared__ float ctxs[C];
    __shared__ float upds[C];
    __shared__ float hid[2 * C];

    for (int v = tid; v < 512; v += 256)
        *reinterpret_cast<float4*>(&wei[v * 4]) =
            *reinterpret_cast<const float4*>(weig + (size_t)bn * NH * C + v * 4);
    __syncthreads();

    {   // ctx[j=tid] = wei[h(j),:] . Wv[j,:] + bv[j]
        int h = tid >> 5;
        float a = bv[tid];
        const float* wrow = Wv + (size_t)tid * C;
        const float* wh   = wei + h * C;
        #pragma unroll 8
        for (int c2 = 0; c2 < C; ++c2) a += wh[c2] * wrow[c2];
        ctxs[tid] = a;
    }
    __syncthreads();

    float att = bo[tid];
    {
        const float* wrow = Wo + (size_t)tid * C;
        #pragma unroll 8
        for (int j = 0; j < C; ++j) att += ctxs[j] * wrow[j];
    }
    float upd = mt[(size_t)bn * C + tid] + att;
    upds[tid] = upd;
    __syncthreads();

    #pragma unroll
    for (int r = 0; r < 2; ++r) {
        int k = tid + r * 256;
        float a = b1[k];
        const float* wrow = W1 + (size_t)k * C;
        #pragma unroll 8
        for (int c2 = 0; c2 < C; ++c2) a += upds[c2] * wrow[c2];
        hid[k] = fmaxf(a, 0.f);
    }
    __syncthreads();

    float a = b2[tid];
    const float* wrow = W2 + (size_t)tid * 2 * C;
    #pragma unroll 8
    for (int k = 0; k < 2 * C; ++k) a += hid[k] * wrow[k];
    out[(size_t)bn * C + tid] = upd + a;
}

extern "C" void kernel_launch(void* const* d_in, const int* in_sizes, int n_in,
                              void* d_out, int out_size, void* d_ws, size_t ws_size,
                              hipStream_t stream)
{
    const float* mt  = (const float*)d_in[0];
    const float* pe  = (const float*)d_in[1];
    const float* ltw = (const float*)d_in[2];
    const float* ltb = (const float*)d_in[3];
    const float* lpw = (const float*)d_in[4];
    const float* lpb = (const float*)d_in[5];
    const float* Wq  = (const float*)d_in[6];
    const float* bq  = (const float*)d_in[7];
    const float* Wk  = (const float*)d_in[8];
    const float* bk  = (const float*)d_in[9];
    const float* Wv  = (const float*)d_in[10];
    const float* bv  = (const float*)d_in[11];
    const float* Wo  = (const float*)d_in[12];
    const float* bo  = (const float*)d_in[13];
    const float* W1  = (const float*)d_in[14];
    const float* b1  = (const float*)d_in[15];
    const float* W2  = (const float*)d_in[16];
    const float* b2  = (const float*)d_in[17];

    float* ws   = (float*)d_ws;
    float* outp = (float*)d_out;

    float* gw   = ws + OFF_GW;
    float* Gv   = ws + OFF_G;
    float* Bc   = ws + OFF_BC;
    float* LP   = ws + OFF_LP;
    float* ZP   = ws + OFF_ZP;
    float* ILv  = ws + OFF_IL;
    float* z    = ws + OFF_Z;
    float* Mp   = ws + OFF_MP;
    float* weig = ws + OFF_WEI;

    k1_prep   <<<64,   256, 0, stream>>>(mt, ltw, ltb, lpw, lpb, Wq, bq, Wk, bk, gw, Gv, Bc);
    kfused    <<<1024, 256, 0, stream>>>(pe, gw, Gv, Bc, LP, ZP, Mp);
    k3_combine<<<8,    64,  0, stream>>>(LP, ZP, ILv, z);
    kfold     <<<512,  256, 0, stream>>>(Mp, ILv, z, lpw, lpb, weig);
    k5_out    <<<64,   256, 0, stream>>>(mt, weig, Wv, bv, Wo, bo, W1, b1, W2, b2, outp);
}